// Round 11
// baseline (358.665 us; speedup 1.0000x reference)
//
#include <hip/hip_runtime.h>

#define BB 32
#define TT 2048
#define SS 32
#define DD 80
#define HH 256
#define VV 1024
#define EBD 64

typedef unsigned short u16;
typedef __attribute__((ext_vector_type(8))) __bf16 bf16x8;
typedef __attribute__((ext_vector_type(4))) float f32x4;

#define MFMA(a, b, c) __builtin_amdgcn_mfma_f32_16x16x32_bf16(a, b, c, 0, 0, 0)

__device__ inline u16 f2bu(float f) {
    unsigned u = __float_as_uint(f);
    return (u16)((u + 0x7FFFu + ((u >> 16) & 1u)) >> 16);
}
__device__ inline __bf16 f2b(float f) {
    u16 r = f2bu(f);
    return __builtin_bit_cast(__bf16, r);
}
__device__ inline float b2f(u16 h) { return __uint_as_float(((unsigned)h) << 16); }

// A/B fragment (16 rows x 32 k) from bf16 row-major [.][256]
__device__ inline bf16x8 ldfrag(const u16* base, int row, int k0, int lane) {
    return *(const bf16x8*)(base + (size_t)row * 256 + k0 + ((lane >> 4) << 3));
}
// same from row-major [.][96]
__device__ inline bf16x8 ldfrag96(const u16* base, int row, int k0, int lane) {
    return *(const bf16x8*)(base + (size_t)row * 96 + k0 + ((lane >> 4) << 3));
}

// ---------------------------------------------------------------------------
// Kernel P: convert GEMM weights f32 -> bf16 once per launch. (round-10 exact)
// ---------------------------------------------------------------------------
__global__ __launch_bounds__(256) void k_prep(const float* __restrict__ w1,
                                              const float* __restrict__ w2,
                                              const float* __restrict__ wp,
                                              const float* __restrict__ ow,
                                              const float* __restrict__ iw,
                                              u16* __restrict__ wbf) {
    int i = blockIdx.x * 256 + threadIdx.x;
    if (i >= 483328) return;
    float v;
    if (i < 65536) v = w1[i];
    else if (i < 131072) v = w2[i - 65536];
    else if (i < 196608) v = wp[i - 131072];
    else if (i < 458752) v = ow[i - 196608];
    else {
        int j = i - 458752;
        int row = j / 96, col = j % 96;
        v = (col < 80) ? iw[row * 80 + col] : 0.f;
    }
    wbf[i] = f2bu(v);
}

// ---------------------------------------------------------------------------
// Kernel A: polynomial rolling hashes + table gathers (round-10 exact)
// ---------------------------------------------------------------------------
__global__ __launch_bounds__(256) void k_hash(const int* __restrict__ tok,
                                              const float* __restrict__ t0,
                                              const float* __restrict__ t1,
                                              const float* __restrict__ t2,
                                              const float* __restrict__ t3,
                                              const float* __restrict__ cond_w,
                                              float* __restrict__ raw) {
    int idx = blockIdx.x * 256 + threadIdx.x;
    if (idx >= BB * TT) return;
    int b = idx / TT, t = idx % TT;
    const int* tr = tok + b * TT;

    unsigned long long tv[8];
#pragma unroll
    for (int i = 0; i < 8; i++) {
        int ts = t - 1 - i;
        tv[i] = (ts >= 0) ? (unsigned long long)(unsigned)tr[ts] : 0ull;
    }
    const unsigned long long P[8] = {2654435761ull, 2246822519ull, 3266489917ull,
                                     2028178513ull, 1220703125ull, 1610612741ull,
                                     805306457ull, 402653189ull};
    unsigned long long x = 0ull;
    x ^= tv[0] * P[0]; unsigned long long k0 = x % 2000000ull;
    x ^= tv[1] * P[1]; unsigned long long k1 = x % 2000000ull;
    x ^= tv[2] * P[2]; x ^= tv[3] * P[3]; unsigned long long k2 = x % 2000000ull;
    x ^= tv[4] * P[4]; x ^= tv[5] * P[5];
    x ^= tv[6] * P[6]; x ^= tv[7] * P[7]; unsigned long long k3 = x % 2000000ull;

    float f0 = t0[k0 * 2], f1 = t0[k0 * 2 + 1];
    float f2 = t1[k1 * 2], f3 = t1[k1 * 2 + 1];

    unsigned long long ck = 0ull;
#pragma unroll
    for (int j = 0; j < 8; j++) {
        float lg = f0 * cond_w[j * 4 + 0] + f1 * cond_w[j * 4 + 1] +
                   f2 * cond_w[j * 4 + 2] + f3 * cond_w[j * 4 + 3];
        if (lg > 0.f) ck ^= P[j];
    }
    unsigned long long lk2 = (k2 ^ ck) % 2000000ull;
    unsigned long long lk3 = (k3 ^ ck) % 2000000ull;

    float* o = raw + (size_t)idx * 8;
    o[0] = f0; o[1] = f1; o[2] = f2; o[3] = f3;
    o[4] = t2[lk2 * 2]; o[5] = t2[lk2 * 2 + 1];
    o[6] = t3[lk3 * 2]; o[7] = t3[lk3 * 2 + 1];
}

// ---------------------------------------------------------------------------
// Kernel B+C fused: per 64-token tile, build h (embed/conv/match, f32,
// same expressions as round-10 k_feat -> identical bits) into LDS + global
// hf, then run the round-10 k_gates dot from LDS. Ag/Dr outputs identical.
// ---------------------------------------------------------------------------
__global__ __launch_bounds__(256) void k_featgates(const int* __restrict__ tok,
                                                   const float* __restrict__ be,
                                                   const float* __restrict__ raw,
                                                   const float* __restrict__ conv_w,
                                                   const float* __restrict__ conv_b,
                                                   const float* __restrict__ gw,
                                                   const float* __restrict__ gb,
                                                   const float* __restrict__ iw,
                                                   const float* __restrict__ ib,
                                                   float* __restrict__ hf,
                                                   float* __restrict__ Ag,
                                                   float* __restrict__ Dr) {
    __shared__ float xs[64][DD];
    __shared__ float gws[32 * 81];
    __shared__ float iws[32 * 81];
    int blk = blockIdx.x;
    int b = blk >> 5;
    int t0 = (blk & 31) << 6;
    int tid = threadIdx.x;
    const int* tr = tok + b * TT;

    for (int i = tid; i < 32 * 80; i += 256) {
        int s = i / 80, d = i % 80;
        gws[s * 81 + d] = gw[i];
        iws[s * 81 + d] = iw[i];
    }

    // embed: 64 tokens x 16 f32x4 chunks
    for (int i = tid; i < 1024; i += 256) {
        int row = i >> 4, q = i & 15;
        int t = t0 + row;
        int tk = tr[t];
        f32x4 v = *(const f32x4*)(be + (size_t)tk * EBD + q * 4);
        *(f32x4*)&xs[row][q * 4] = v;
        *(f32x4*)(hf + ((size_t)(b * TT + t)) * DD + q * 4) = v;
    }

    // conv + match: thread tid<64 owns token t0+tid (same math as k_feat)
    if (tid < 64) {
        int t = t0 + tid;
        int tk = tr[t];
        float* o = hf + ((size_t)(b * TT + t)) * DD;
#pragma unroll
        for (int c = 0; c < 8; c++) {
            float acc = conv_b[c];
#pragma unroll
            for (int k = 0; k < 8; k++) {
                int ts = t - 7 + k;
                if (ts >= 0) acc += conv_w[c * 8 + k] * raw[((size_t)(b * TT + ts)) * 8 + c];
            }
            float sv = acc / (1.f + expf(-acc));
            xs[tid][64 + c] = sv;
            o[64 + c] = sv;
        }
#pragma unroll
        for (int k = 1; k <= 8; k++) {
            float m = (t >= k && tk == tr[t - k]) ? 1.f : 0.f;
            xs[tid][71 + k] = m;
            o[71 + k] = m;
        }
    }
    __syncthreads();

    // gates dot (round-10 exact arithmetic)
    for (int p = tid; p < 64 * SS; p += 256) {
        int s = p & 31, tt = p >> 5;
        float ga = gb[s], ia = ib[s];
        for (int d = 0; d < DD; d++) {
            float xv = xs[tt][d];
            ga += xv * gws[s * 81 + d];
            ia += xv * iws[s * 81 + d];
        }
        float g = 1.f / (1.f + expf(-ga));
        float drv = (1.f - g) * ia;
        size_t oo = ((size_t)(b * SS + s)) * TT + t0 + tt;
        Ag[oo] = g;
        Dr[oo] = drv;
    }
}

// ---------------------------------------------------------------------------
// Kernel D: parallel chunked scan (round-10 exact)
// ---------------------------------------------------------------------------
__global__ __launch_bounds__(64) void k_scan_par(const float* __restrict__ Ag,
                                                 const float* __restrict__ Dr,
                                                 float* __restrict__ st) {
    int bs = blockIdx.x;
    int b = bs >> 5, s = bs & 31;
    int c = threadIdx.x;
    const float* ar = Ag + (size_t)bs * TT + c * 32;
    const float* dr = Dr + (size_t)bs * TT + c * 32;

    float ca[32], cw[32];
    float lacc = 0.f, wacc = 0.f;
#pragma unroll
    for (int k = 0; k < 32; k += 4) {
        f32x4 av = *(const f32x4*)(ar + k);
        f32x4 dv = *(const f32x4*)(dr + k);
#pragma unroll
        for (int j = 0; j < 4; j++) {
            lacc += logf(fmaxf(av[j], 1e-6f));
            float cav = expf(lacc);
            ca[k + j] = cav;
            wacc += dv[j] / fmaxf(cav, 1e-8f);
            cw[k + j] = wacc;
        }
    }

    float A = ca[31];
    float Bc = ca[31] * wacc;
    for (int off = 1; off < 64; off <<= 1) {
        float Ap = __shfl_up(A, off, 64);
        float Bp = __shfl_up(Bc, off, 64);
        if (c >= off) {
            Bc = A * Bp + Bc;
            A = A * Ap;
        }
    }
    float h0 = __shfl_up(Bc, 1, 64);
    if (c == 0) h0 = 0.f;

    float* op = st + ((size_t)(b * TT + c * 32)) * SS + s;
#pragma unroll
    for (int k = 0; k < 32; k++)
        op[(size_t)k * SS] = ca[k] * (h0 + cw[k]);
}

// ---------------------------------------------------------------------------
// Kernel E: y = st @ outpr_w^T + ob; h1 = LN(hf + y) -> h1p bf16[96] (round-10)
// ---------------------------------------------------------------------------
__global__ __launch_bounds__(256) void k_post(const float* __restrict__ st,
                                              const float* __restrict__ hf,
                                              const float* __restrict__ ow,
                                              const float* __restrict__ ob,
                                              const float* __restrict__ lnw,
                                              const float* __restrict__ lnb,
                                              u16* __restrict__ h1p) {
    __shared__ float ows[DD * SS];
    for (int i = threadIdx.x; i < DD * SS; i += 256) ows[i] = ow[i];
    __syncthreads();

    int idx = blockIdx.x * 256 + threadIdx.x;
    if (idx >= BB * TT) return;
    const float* sp = st + (size_t)idx * SS;
    float sv[SS];
#pragma unroll
    for (int i = 0; i < SS; i += 4) {
        f32x4 v4 = *(const f32x4*)(sp + i);
        sv[i] = v4[0]; sv[i + 1] = v4[1]; sv[i + 2] = v4[2]; sv[i + 3] = v4[3];
    }
    const float* x = hf + (size_t)idx * DD;

    float s1 = 0.f, s2 = 0.f;
    for (int d = 0; d < DD; d++) {
        float acc = ob[d];
#pragma unroll
        for (int i = 0; i < SS; i++) acc += sv[i] * ows[d * SS + i];
        float v = acc + x[d];
        s1 += v; s2 += v * v;
    }
    float m = s1 * (1.f / DD);
    float var = s2 * (1.f / DD) - m * m;
    float rs = rsqrtf(var + 1e-5f);
    u16* o = h1p + (size_t)idx * 96;
    for (int d = 0; d < DD; d++) {
        float acc = ob[d];
#pragma unroll
        for (int i = 0; i < SS; i++) acc += sv[i] * ows[d * SS + i];
        float v = acc + x[d];
        o[d] = f2bu((v - m) * rs * lnw[d] + lnb[d]);
    }
    *(f32x4*)(o + 80) = f32x4{0.f, 0.f, 0.f, 0.f};
    *(f32x4*)(o + 88) = f32x4{0.f, 0.f, 0.f, 0.f};
}

// ---------------------------------------------------------------------------
// Kernel F+H fused (MFMA): per 64-row block:
//   phase1: X = silu(h1p @ inp_w^T + b)      -> LDS Xs
//   phase2: U = silu(X@w1^T) * (X@w2^T)      -> LDS Us
//   phase3: h3 = LN(U@wp^T + X)              -> back into Xs (Xs dead after
//            the stats pass; barrier-protected)
//   phase4: out = h3 @ out_w^T + out_b       -> global f32 (barrier-free;
//            A from LDS, B=out_w L2-resident). MFMA sequences and operand
//            values identical to round-10 k_gmlp_f + k_out4 => bit-identical.
// ---------------------------------------------------------------------------
#define SX 264
__global__ __launch_bounds__(256) void k_gmlp_out(const u16* __restrict__ h1p,
                                                  const u16* __restrict__ iwb,
                                                  const float* __restrict__ ibias,
                                                  const u16* __restrict__ w1,
                                                  const u16* __restrict__ w2,
                                                  const u16* __restrict__ wp,
                                                  const float* __restrict__ lnw,
                                                  const float* __restrict__ lnb,
                                                  const u16* __restrict__ ow,
                                                  const float* __restrict__ obias,
                                                  float* __restrict__ out) {
    __shared__ u16 Xs[64 * SX];
    __shared__ u16 Us[64 * SX];
    __shared__ float redS[64][4], redQ[64][4];
    int lane = threadIdx.x & 63, wv = threadIdx.x >> 6;
    int r0 = blockIdx.x * 64;
    int g = lane >> 4, cl = lane & 15, rl = lane & 15;

    // ---- phase 1: mlp1 (K=96) ----
    {
        int c0 = wv * 64;
        f32x4 acc[4][4] = {};
#pragma unroll
        for (int ks = 0; ks < 3; ks++) {
            int k0 = ks * 32;
            bf16x8 a[4];
#pragma unroll
            for (int mi = 0; mi < 4; mi++) a[mi] = ldfrag96(h1p, r0 + mi * 16 + rl, k0, lane);
#pragma unroll
            for (int ni = 0; ni < 4; ni++) {
                bf16x8 b = ldfrag96(iwb, c0 + ni * 16 + rl, k0, lane);
#pragma unroll
                for (int mi = 0; mi < 4; mi++) acc[mi][ni] = MFMA(a[mi], b, acc[mi][ni]);
            }
        }
#pragma unroll
        for (int ni = 0; ni < 4; ni++) {
            float bv = ibias[c0 + ni * 16 + cl];
#pragma unroll
            for (int mi = 0; mi < 4; mi++)
#pragma unroll
                for (int r = 0; r < 4; r++) {
                    float v = acc[mi][ni][r] + bv;
                    Xs[(mi * 16 + g * 4 + r) * SX + c0 + ni * 16 + cl] =
                        f2bu(v / (1.f + expf(-v)));
                }
        }
    }
    __syncthreads();

    // ---- phase 2: gemm_u (K=256) ----
    for (int cg = 0; cg < 2; cg++) {
        int c0 = cg * 128 + wv * 32;
        f32x4 a1[4][2] = {}, a2[4][2] = {};
        for (int ks = 0; ks < 8; ks++) {
            int k0 = ks * 32 + (g << 3);
            bf16x8 a[4];
#pragma unroll
            for (int mi = 0; mi < 4; mi++)
                a[mi] = *(const bf16x8*)&Xs[(mi * 16 + rl) * SX + k0];
#pragma unroll
            for (int ni = 0; ni < 2; ni++) {
                bf16x8 b1 = ldfrag(w1, c0 + ni * 16 + rl, ks * 32, lane);
                bf16x8 b2 = ldfrag(w2, c0 + ni * 16 + rl, ks * 32, lane);
#pragma unroll
                for (int mi = 0; mi < 4; mi++) {
                    a1[mi][ni] = MFMA(a[mi], b1, a1[mi][ni]);
                    a2[mi][ni] = MFMA(a[mi], b2, a2[mi][ni]);
                }
            }
        }
#pragma unroll
        for (int mi = 0; mi < 4; mi++)
#pragma unroll
            for (int ni = 0; ni < 2; ni++)
#pragma unroll
                for (int r = 0; r < 4; r++) {
                    float v1 = a1[mi][ni][r], v2 = a2[mi][ni][r];
                    float u = v1 / (1.f + expf(-v1)) * v2;
                    Us[(mi * 16 + g * 4 + r) * SX + cg * 128 + wv * 32 + ni * 16 + cl] = f2bu(u);
                }
    }
    __syncthreads();

    // ---- phase 3: proj (K=256) + residual + LN -> h3 into Xs ----
    {
        int c0 = wv * 64;
        f32x4 acc[4][4] = {};
        for (int ks = 0; ks < 8; ks++) {
            int k0 = ks * 32 + (g << 3);
            bf16x8 a[4];
#pragma unroll
            for (int mi = 0; mi < 4; mi++)
                a[mi] = *(const bf16x8*)&Us[(mi * 16 + rl) * SX + k0];
#pragma unroll
            for (int ni = 0; ni < 4; ni++) {
                bf16x8 b = ldfrag(wp, c0 + ni * 16 + rl, ks * 32, lane);
#pragma unroll
                for (int mi = 0; mi < 4; mi++) acc[mi][ni] = MFMA(a[mi], b, acc[mi][ni]);
            }
        }
#pragma unroll
        for (int mi = 0; mi < 4; mi++)
#pragma unroll
            for (int r = 0; r < 4; r++) {
                float s = 0.f, q = 0.f;
                int row = mi * 16 + g * 4 + r;
#pragma unroll
                for (int ni = 0; ni < 4; ni++) {
                    int col = c0 + ni * 16 + cl;
                    float v = acc[mi][ni][r] + b2f(Xs[row * SX + col]);
                    acc[mi][ni][r] = v;
                    s += v; q += v * v;
                }
                for (int m = 1; m < 16; m <<= 1) {
                    s += __shfl_xor(s, m, 64);
                    q += __shfl_xor(q, m, 64);
                }
                if (cl == 0) { redS[row][wv] = s; redQ[row][wv] = q; }
            }
        __syncthreads();   // all Xs reads done; redS/redQ visible

        float lw[4], lb[4];
#pragma unroll
        for (int ni = 0; ni < 4; ni++) {
            lw[ni] = lnw[c0 + ni * 16 + cl];
            lb[ni] = lnb[c0 + ni * 16 + cl];
        }
#pragma unroll
        for (int mi = 0; mi < 4; mi++)
#pragma unroll
            for (int r = 0; r < 4; r++) {
                int row = mi * 16 + g * 4 + r;
                float S = redS[row][0] + redS[row][1] + redS[row][2] + redS[row][3];
                float Q = redQ[row][0] + redQ[row][1] + redQ[row][2] + redQ[row][3];
                float m = S * (1.f / 256.f);
                float rs = rsqrtf(Q * (1.f / 256.f) - m * m + 1e-5f);
#pragma unroll
                for (int ni = 0; ni < 4; ni++) {
                    float y = (acc[mi][ni][r] - m) * rs * lw[ni] + lb[ni];
                    Xs[row * SX + c0 + ni * 16 + cl] = f2bu(y);   // h3 in LDS
                }
            }
    }
    __syncthreads();

    // ---- phase 4: out GEMM (K=256), barrier-free; A=h3 from Xs, B from L2 ----
    for (int cg = 0; cg < 4; cg++) {
        int c0 = cg * 256 + wv * 64;
        f32x4 acc[4][4] = {};
        for (int ks = 0; ks < 8; ks++) {
            int k0 = ks * 32 + (g << 3);
            bf16x8 a[4];
#pragma unroll
            for (int mi = 0; mi < 4; mi++)
                a[mi] = *(const bf16x8*)&Xs[(mi * 16 + rl) * SX + k0];
#pragma unroll
            for (int ni = 0; ni < 4; ni++) {
                bf16x8 b = ldfrag(ow, c0 + ni * 16 + rl, ks * 32, lane);
#pragma unroll
                for (int mi = 0; mi < 4; mi++) acc[mi][ni] = MFMA(a[mi], b, acc[mi][ni]);
            }
        }
#pragma unroll
        for (int ni = 0; ni < 4; ni++) {
            float bv = obias[c0 + ni * 16 + cl];
#pragma unroll
            for (int mi = 0; mi < 4; mi++)
#pragma unroll
                for (int r = 0; r < 4; r++)
                    out[(size_t)(r0 + mi * 16 + g * 4 + r) * VV + c0 + ni * 16 + cl] =
                        acc[mi][ni][r] + bv;
        }
    }
}

// ---------------------------------------------------------------------------
extern "C" void kernel_launch(void* const* d_in, const int* in_sizes, int n_in,
                              void* d_out, int out_size, void* d_ws, size_t ws_size,
                              hipStream_t stream) {
    const int* chars        = (const int*)d_in[0];
    const float* byte_embed = (const float*)d_in[1];
    const float* table0     = (const float*)d_in[2];
    const float* table1     = (const float*)d_in[3];
    const float* table2     = (const float*)d_in[4];
    const float* table3     = (const float*)d_in[5];
    const float* cond_w     = (const float*)d_in[6];
    const float* conv_w     = (const float*)d_in[7];
    const float* conv_b     = (const float*)d_in[8];
    const float* gate_w     = (const float*)d_in[9];
    const float* gate_b     = (const float*)d_in[10];
    const float* inpr_w     = (const float*)d_in[11];
    const float* inpr_b     = (const float*)d_in[12];
    const float* outpr_w    = (const float*)d_in[13];
    const float* outpr_b    = (const float*)d_in[14];
    const float* scan_ln_w  = (const float*)d_in[15];
    const float* scan_ln_b  = (const float*)d_in[16];
    const float* inp_w      = (const float*)d_in[17];
    const float* inp_b      = (const float*)d_in[18];
    const float* r_w1       = (const float*)d_in[19];
    const float* r_w2       = (const float*)d_in[20];
    const float* r_proj     = (const float*)d_in[21];
    const float* r_ln_w     = (const float*)d_in[22];
    const float* r_ln_b     = (const float*)d_in[23];
    const float* out_w      = (const float*)d_in[24];
    const float* out_b      = (const float*)d_in[25];

    // ws layout, fully disjoint (peak 61.9 MB):
    //   wbf  [0, 0.97M)       prep..end
    //   hf   [1M, 22M)        featgates..post (f32, stride 80)
    //   raw  [22M, 24.1M)     hash..featgates
    //   Ag   [24.1M, 32.5M)   featgates..scan
    //   Dr   [32.5M, 40.9M)   featgates..scan
    //   st   [40.9M, 49.3M)   scan..post
    //   h1p  [49.3M, 61.9M)   post..gmlp_out (bf16, stride 96)
    char* ws = (char*)d_ws;
    u16*   wbf = (u16*)(ws + 0);
    u16*   w1b = wbf;
    u16*   w2b = wbf + 65536;
    u16*   wpb = wbf + 131072;
    u16*   owb = wbf + 196608;
    u16*   iwb = wbf + 458752;
    float* hf  = (float*)(ws + 1048576);
    float* raw = (float*)(ws + 23068672);
    float* Ag  = (float*)(ws + 25165824);
    float* Dr  = (float*)(ws + 33554432);
    float* st  = (float*)(ws + 41943040);
    u16*   h1p = (u16*)(ws + 50331648);
    float* out = (float*)d_out;

    k_prep <<<1888, 256, 0, stream>>>(r_w1, r_w2, r_proj, out_w, inp_w, wbf);
    k_hash <<<256, 256, 0, stream>>>(chars, table0, table1, table2, table3, cond_w, raw);
    k_featgates<<<1024, 256, 0, stream>>>(chars, byte_embed, raw, conv_w, conv_b,
                                          gate_w, gate_b, inpr_w, inpr_b, hf, Ag, Dr);
    k_scan_par<<<1024, 64, 0, stream>>>(Ag, Dr, st);
    k_post <<<256, 256, 0, stream>>>(st, hf, outpr_w, outpr_b, scan_ln_w, scan_ln_b, h1p);
    k_gmlp_out<<<1024, 256, 0, stream>>>(h1p, iwb, inp_b, w1b, w2b, wpb,
                                         r_ln_w, r_ln_b, owb, out_b, out);
}

// Round 12
// 335.174 us; speedup vs baseline: 1.0701x; 1.0701x over previous
//
#include <hip/hip_runtime.h>

#define BB 32
#define TT 2048
#define SS 32
#define DD 80
#define HH 256
#define VV 1024
#define EBD 64

typedef unsigned short u16;
typedef __attribute__((ext_vector_type(8))) __bf16 bf16x8;
typedef __attribute__((ext_vector_type(4))) float f32x4;

#define MFMA(a, b, c) __builtin_amdgcn_mfma_f32_16x16x32_bf16(a, b, c, 0, 0, 0)

__device__ inline u16 f2bu(float f) {
    unsigned u = __float_as_uint(f);
    return (u16)((u + 0x7FFFu + ((u >> 16) & 1u)) >> 16);
}
__device__ inline __bf16 f2b(float f) {
    u16 r = f2bu(f);
    return __builtin_bit_cast(__bf16, r);
}
__device__ inline float b2f(u16 h) { return __uint_as_float(((unsigned)h) << 16); }

// A/B fragment (16 rows x 32 k) from bf16 row-major [.][256]
__device__ inline bf16x8 ldfrag(const u16* base, int row, int k0, int lane) {
    return *(const bf16x8*)(base + (size_t)row * 256 + k0 + ((lane >> 4) << 3));
}
// same from row-major [.][96]
__device__ inline bf16x8 ldfrag96(const u16* base, int row, int k0, int lane) {
    return *(const bf16x8*)(base + (size_t)row * 96 + k0 + ((lane >> 4) << 3));
}

// ---------------------------------------------------------------------------
// Kernel P: convert GEMM weights f32 -> bf16 once per launch. (round-10 exact)
// ---------------------------------------------------------------------------
__global__ __launch_bounds__(256) void k_prep(const float* __restrict__ w1,
                                              const float* __restrict__ w2,
                                              const float* __restrict__ wp,
                                              const float* __restrict__ ow,
                                              const float* __restrict__ iw,
                                              u16* __restrict__ wbf) {
    int i = blockIdx.x * 256 + threadIdx.x;
    if (i >= 483328) return;
    float v;
    if (i < 65536) v = w1[i];
    else if (i < 131072) v = w2[i - 65536];
    else if (i < 196608) v = wp[i - 131072];
    else if (i < 458752) v = ow[i - 196608];
    else {
        int j = i - 458752;
        int row = j / 96, col = j % 96;
        v = (col < 80) ? iw[row * 80 + col] : 0.f;
    }
    wbf[i] = f2bu(v);
}

// ---------------------------------------------------------------------------
// Kernel A: polynomial rolling hashes + table gathers (round-10 exact)
// ---------------------------------------------------------------------------
__global__ __launch_bounds__(256) void k_hash(const int* __restrict__ tok,
                                              const float* __restrict__ t0,
                                              const float* __restrict__ t1,
                                              const float* __restrict__ t2,
                                              const float* __restrict__ t3,
                                              const float* __restrict__ cond_w,
                                              float* __restrict__ raw) {
    int idx = blockIdx.x * 256 + threadIdx.x;
    if (idx >= BB * TT) return;
    int b = idx / TT, t = idx % TT;
    const int* tr = tok + b * TT;

    unsigned long long tv[8];
#pragma unroll
    for (int i = 0; i < 8; i++) {
        int ts = t - 1 - i;
        tv[i] = (ts >= 0) ? (unsigned long long)(unsigned)tr[ts] : 0ull;
    }
    const unsigned long long P[8] = {2654435761ull, 2246822519ull, 3266489917ull,
                                     2028178513ull, 1220703125ull, 1610612741ull,
                                     805306457ull, 402653189ull};
    unsigned long long x = 0ull;
    x ^= tv[0] * P[0]; unsigned long long k0 = x % 2000000ull;
    x ^= tv[1] * P[1]; unsigned long long k1 = x % 2000000ull;
    x ^= tv[2] * P[2]; x ^= tv[3] * P[3]; unsigned long long k2 = x % 2000000ull;
    x ^= tv[4] * P[4]; x ^= tv[5] * P[5];
    x ^= tv[6] * P[6]; x ^= tv[7] * P[7]; unsigned long long k3 = x % 2000000ull;

    float f0 = t0[k0 * 2], f1 = t0[k0 * 2 + 1];
    float f2 = t1[k1 * 2], f3 = t1[k1 * 2 + 1];

    unsigned long long ck = 0ull;
#pragma unroll
    for (int j = 0; j < 8; j++) {
        float lg = f0 * cond_w[j * 4 + 0] + f1 * cond_w[j * 4 + 1] +
                   f2 * cond_w[j * 4 + 2] + f3 * cond_w[j * 4 + 3];
        if (lg > 0.f) ck ^= P[j];
    }
    unsigned long long lk2 = (k2 ^ ck) % 2000000ull;
    unsigned long long lk3 = (k3 ^ ck) % 2000000ull;

    float* o = raw + (size_t)idx * 8;
    o[0] = f0; o[1] = f1; o[2] = f2; o[3] = f3;
    o[4] = t2[lk2 * 2]; o[5] = t2[lk2 * 2 + 1];
    o[6] = t3[lk3 * 2]; o[7] = t3[lk3 * 2 + 1];
}

// ---------------------------------------------------------------------------
// Kernel B+C fused (round-11 exact — retained: bit-identical math, one launch
// fewer, no 20 MB hf re-read)
// ---------------------------------------------------------------------------
__global__ __launch_bounds__(256) void k_featgates(const int* __restrict__ tok,
                                                   const float* __restrict__ be,
                                                   const float* __restrict__ raw,
                                                   const float* __restrict__ conv_w,
                                                   const float* __restrict__ conv_b,
                                                   const float* __restrict__ gw,
                                                   const float* __restrict__ gb,
                                                   const float* __restrict__ iw,
                                                   const float* __restrict__ ib,
                                                   float* __restrict__ hf,
                                                   float* __restrict__ Ag,
                                                   float* __restrict__ Dr) {
    __shared__ float xs[64][DD];
    __shared__ float gws[32 * 81];
    __shared__ float iws[32 * 81];
    int blk = blockIdx.x;
    int b = blk >> 5;
    int t0 = (blk & 31) << 6;
    int tid = threadIdx.x;
    const int* tr = tok + b * TT;

    for (int i = tid; i < 32 * 80; i += 256) {
        int s = i / 80, d = i % 80;
        gws[s * 81 + d] = gw[i];
        iws[s * 81 + d] = iw[i];
    }

    for (int i = tid; i < 1024; i += 256) {
        int row = i >> 4, q = i & 15;
        int t = t0 + row;
        int tk = tr[t];
        f32x4 v = *(const f32x4*)(be + (size_t)tk * EBD + q * 4);
        *(f32x4*)&xs[row][q * 4] = v;
        *(f32x4*)(hf + ((size_t)(b * TT + t)) * DD + q * 4) = v;
    }

    if (tid < 64) {
        int t = t0 + tid;
        int tk = tr[t];
        float* o = hf + ((size_t)(b * TT + t)) * DD;
#pragma unroll
        for (int c = 0; c < 8; c++) {
            float acc = conv_b[c];
#pragma unroll
            for (int k = 0; k < 8; k++) {
                int ts = t - 7 + k;
                if (ts >= 0) acc += conv_w[c * 8 + k] * raw[((size_t)(b * TT + ts)) * 8 + c];
            }
            float sv = acc / (1.f + expf(-acc));
            xs[tid][64 + c] = sv;
            o[64 + c] = sv;
        }
#pragma unroll
        for (int k = 1; k <= 8; k++) {
            float m = (t >= k && tk == tr[t - k]) ? 1.f : 0.f;
            xs[tid][71 + k] = m;
            o[71 + k] = m;
        }
    }
    __syncthreads();

    for (int p = tid; p < 64 * SS; p += 256) {
        int s = p & 31, tt = p >> 5;
        float ga = gb[s], ia = ib[s];
        for (int d = 0; d < DD; d++) {
            float xv = xs[tt][d];
            ga += xv * gws[s * 81 + d];
            ia += xv * iws[s * 81 + d];
        }
        float g = 1.f / (1.f + expf(-ga));
        float drv = (1.f - g) * ia;
        size_t oo = ((size_t)(b * SS + s)) * TT + t0 + tt;
        Ag[oo] = g;
        Dr[oo] = drv;
    }
}

// ---------------------------------------------------------------------------
// Kernel D: parallel chunked scan (round-10 exact)
// ---------------------------------------------------------------------------
__global__ __launch_bounds__(64) void k_scan_par(const float* __restrict__ Ag,
                                                 const float* __restrict__ Dr,
                                                 float* __restrict__ st) {
    int bs = blockIdx.x;
    int b = bs >> 5, s = bs & 31;
    int c = threadIdx.x;
    const float* ar = Ag + (size_t)bs * TT + c * 32;
    const float* dr = Dr + (size_t)bs * TT + c * 32;

    float ca[32], cw[32];
    float lacc = 0.f, wacc = 0.f;
#pragma unroll
    for (int k = 0; k < 32; k += 4) {
        f32x4 av = *(const f32x4*)(ar + k);
        f32x4 dv = *(const f32x4*)(dr + k);
#pragma unroll
        for (int j = 0; j < 4; j++) {
            lacc += logf(fmaxf(av[j], 1e-6f));
            float cav = expf(lacc);
            ca[k + j] = cav;
            wacc += dv[j] / fmaxf(cav, 1e-8f);
            cw[k + j] = wacc;
        }
    }

    float A = ca[31];
    float Bc = ca[31] * wacc;
    for (int off = 1; off < 64; off <<= 1) {
        float Ap = __shfl_up(A, off, 64);
        float Bp = __shfl_up(Bc, off, 64);
        if (c >= off) {
            Bc = A * Bp + Bc;
            A = A * Ap;
        }
    }
    float h0 = __shfl_up(Bc, 1, 64);
    if (c == 0) h0 = 0.f;

    float* op = st + ((size_t)(b * TT + c * 32)) * SS + s;
#pragma unroll
    for (int k = 0; k < 32; k++)
        op[(size_t)k * SS] = ca[k] * (h0 + cw[k]);
}

// ---------------------------------------------------------------------------
// Kernel E: y = st @ outpr_w^T + ob; h1 = LN(hf + y) -> h1p bf16[96] (round-10)
// ---------------------------------------------------------------------------
__global__ __launch_bounds__(256) void k_post(const float* __restrict__ st,
                                              const float* __restrict__ hf,
                                              const float* __restrict__ ow,
                                              const float* __restrict__ ob,
                                              const float* __restrict__ lnw,
                                              const float* __restrict__ lnb,
                                              u16* __restrict__ h1p) {
    __shared__ float ows[DD * SS];
    for (int i = threadIdx.x; i < DD * SS; i += 256) ows[i] = ow[i];
    __syncthreads();

    int idx = blockIdx.x * 256 + threadIdx.x;
    if (idx >= BB * TT) return;
    const float* sp = st + (size_t)idx * SS;
    float sv[SS];
#pragma unroll
    for (int i = 0; i < SS; i += 4) {
        f32x4 v4 = *(const f32x4*)(sp + i);
        sv[i] = v4[0]; sv[i + 1] = v4[1]; sv[i + 2] = v4[2]; sv[i + 3] = v4[3];
    }
    const float* x = hf + (size_t)idx * DD;

    float s1 = 0.f, s2 = 0.f;
    for (int d = 0; d < DD; d++) {
        float acc = ob[d];
#pragma unroll
        for (int i = 0; i < SS; i++) acc += sv[i] * ows[d * SS + i];
        float v = acc + x[d];
        s1 += v; s2 += v * v;
    }
    float m = s1 * (1.f / DD);
    float var = s2 * (1.f / DD) - m * m;
    float rs = rsqrtf(var + 1e-5f);
    u16* o = h1p + (size_t)idx * 96;
    for (int d = 0; d < DD; d++) {
        float acc = ob[d];
#pragma unroll
        for (int i = 0; i < SS; i++) acc += sv[i] * ows[d * SS + i];
        float v = acc + x[d];
        o[d] = f2bu((v - m) * rs * lnw[d] + lnb[d]);
    }
    *(f32x4*)(o + 80) = f32x4{0.f, 0.f, 0.f, 0.f};
    *(f32x4*)(o + 88) = f32x4{0.f, 0.f, 0.f, 0.f};
}

// ---------------------------------------------------------------------------
// Kernel F (fused gmlp, MFMA) — round-10 exact
// ---------------------------------------------------------------------------
#define SX 264
__global__ __launch_bounds__(256) void k_gmlp_f(const u16* __restrict__ h1p,
                                                const u16* __restrict__ iwb,
                                                const float* __restrict__ ibias,
                                                const u16* __restrict__ w1,
                                                const u16* __restrict__ w2,
                                                const u16* __restrict__ wp,
                                                const float* __restrict__ lnw,
                                                const float* __restrict__ lnb,
                                                u16* __restrict__ h3) {
    __shared__ u16 Xs[64 * SX];
    __shared__ u16 Us[64 * SX];
    __shared__ float redS[64][4], redQ[64][4];
    int lane = threadIdx.x & 63, wv = threadIdx.x >> 6;
    int r0 = blockIdx.x * 64;
    int g = lane >> 4, cl = lane & 15, rl = lane & 15;

    // ---- phase 1: mlp1 (K=96) ----
    {
        int c0 = wv * 64;
        f32x4 acc[4][4] = {};
#pragma unroll
        for (int ks = 0; ks < 3; ks++) {
            int k0 = ks * 32;
            bf16x8 a[4];
#pragma unroll
            for (int mi = 0; mi < 4; mi++) a[mi] = ldfrag96(h1p, r0 + mi * 16 + rl, k0, lane);
#pragma unroll
            for (int ni = 0; ni < 4; ni++) {
                bf16x8 b = ldfrag96(iwb, c0 + ni * 16 + rl, k0, lane);
#pragma unroll
                for (int mi = 0; mi < 4; mi++) acc[mi][ni] = MFMA(a[mi], b, acc[mi][ni]);
            }
        }
#pragma unroll
        for (int ni = 0; ni < 4; ni++) {
            float bv = ibias[c0 + ni * 16 + cl];
#pragma unroll
            for (int mi = 0; mi < 4; mi++)
#pragma unroll
                for (int r = 0; r < 4; r++) {
                    float v = acc[mi][ni][r] + bv;
                    Xs[(mi * 16 + g * 4 + r) * SX + c0 + ni * 16 + cl] =
                        f2bu(v / (1.f + expf(-v)));
                }
        }
    }
    __syncthreads();

    // ---- phase 2: gemm_u (K=256) ----
    for (int cg = 0; cg < 2; cg++) {
        int c0 = cg * 128 + wv * 32;
        f32x4 a1[4][2] = {}, a2[4][2] = {};
        for (int ks = 0; ks < 8; ks++) {
            int k0 = ks * 32 + (g << 3);
            bf16x8 a[4];
#pragma unroll
            for (int mi = 0; mi < 4; mi++)
                a[mi] = *(const bf16x8*)&Xs[(mi * 16 + rl) * SX + k0];
#pragma unroll
            for (int ni = 0; ni < 2; ni++) {
                bf16x8 b1 = ldfrag(w1, c0 + ni * 16 + rl, ks * 32, lane);
                bf16x8 b2 = ldfrag(w2, c0 + ni * 16 + rl, ks * 32, lane);
#pragma unroll
                for (int mi = 0; mi < 4; mi++) {
                    a1[mi][ni] = MFMA(a[mi], b1, a1[mi][ni]);
                    a2[mi][ni] = MFMA(a[mi], b2, a2[mi][ni]);
                }
            }
        }
#pragma unroll
        for (int mi = 0; mi < 4; mi++)
#pragma unroll
            for (int ni = 0; ni < 2; ni++)
#pragma unroll
                for (int r = 0; r < 4; r++) {
                    float v1 = a1[mi][ni][r], v2 = a2[mi][ni][r];
                    float u = v1 / (1.f + expf(-v1)) * v2;
                    Us[(mi * 16 + g * 4 + r) * SX + c0 + ni * 16 + cl] = f2bu(u);
                }
    }
    __syncthreads();

    // ---- phase 3: proj (K=256) + residual + LN -> h3 global ----
    {
        int c0 = wv * 64;
        f32x4 acc[4][4] = {};
        for (int ks = 0; ks < 8; ks++) {
            int k0 = ks * 32 + (g << 3);
            bf16x8 a[4];
#pragma unroll
            for (int mi = 0; mi < 4; mi++)
                a[mi] = *(const bf16x8*)&Us[(mi * 16 + rl) * SX + k0];
#pragma unroll
            for (int ni = 0; ni < 4; ni++) {
                bf16x8 b = ldfrag(wp, c0 + ni * 16 + rl, ks * 32, lane);
#pragma unroll
                for (int mi = 0; mi < 4; mi++) acc[mi][ni] = MFMA(a[mi], b, acc[mi][ni]);
            }
        }
#pragma unroll
        for (int mi = 0; mi < 4; mi++)
#pragma unroll
            for (int r = 0; r < 4; r++) {
                float s = 0.f, q = 0.f;
                int row = mi * 16 + g * 4 + r;
#pragma unroll
                for (int ni = 0; ni < 4; ni++) {
                    int col = c0 + ni * 16 + cl;
                    float v = acc[mi][ni][r] + b2f(Xs[row * SX + col]);
                    acc[mi][ni][r] = v;
                    s += v; q += v * v;
                }
                for (int m = 1; m < 16; m <<= 1) {
                    s += __shfl_xor(s, m, 64);
                    q += __shfl_xor(q, m, 64);
                }
                if (cl == 0) { redS[row][wv] = s; redQ[row][wv] = q; }
            }
        __syncthreads();

        float lw[4], lb[4];
#pragma unroll
        for (int ni = 0; ni < 4; ni++) {
            lw[ni] = lnw[c0 + ni * 16 + cl];
            lb[ni] = lnb[c0 + ni * 16 + cl];
        }
#pragma unroll
        for (int mi = 0; mi < 4; mi++)
#pragma unroll
            for (int r = 0; r < 4; r++) {
                int row = mi * 16 + g * 4 + r;
                float S = redS[row][0] + redS[row][1] + redS[row][2] + redS[row][3];
                float Q = redQ[row][0] + redQ[row][1] + redQ[row][2] + redQ[row][3];
                float m = S * (1.f / 256.f);
                float rs = rsqrtf(Q * (1.f / 256.f) - m * m + 1e-5f);
#pragma unroll
                for (int ni = 0; ni < 4; ni++) {
                    float y = (acc[mi][ni][r] - m) * rs * lw[ni] + lb[ni];
                    h3[(size_t)(r0 + row) * 256 + c0 + ni * 16 + cl] = f2bu(y);
                }
            }
    }
}

// ---------------------------------------------------------------------------
// Kernel H (MFMA): out = h3 @ out_w^T + out_b — round-10 k_out4 exact
// ---------------------------------------------------------------------------
#define SA 40
__global__ __launch_bounds__(256) void k_out4(const u16* __restrict__ h3,
                                              const u16* __restrict__ ow,
                                              const float* __restrict__ bias,
                                              float* __restrict__ out) {
    __shared__ u16 As[2][128 * SA];
    __shared__ u16 Bs[2][128 * SA];
    int tid = threadIdx.x, lane = tid & 63, wv = tid >> 6;
    int r0 = blockIdx.x * 128;
    int wr = (wv >> 1) * 64, wc = (wv & 1) * 64;
    int rl = lane & 15, g = lane >> 4;

    int row0_ = tid >> 2, cc0_ = tid & 3;
    int row1_ = (tid + 256) >> 2, cc1_ = tid & 3;
    bf16x8 rA0, rA1, rB0, rB1;

#define LOADT(cg, kt)                                                                      \
    {                                                                                      \
        int kbase = (kt) * 32;                                                             \
        int c0g = (cg) * 128;                                                              \
        rA0 = *(const bf16x8*)(h3 + (size_t)(r0 + row0_) * 256 + kbase + cc0_ * 8);        \
        rA1 = *(const bf16x8*)(h3 + (size_t)(r0 + row1_) * 256 + kbase + cc1_ * 8);        \
        rB0 = *(const bf16x8*)(ow + (size_t)(c0g + row0_) * 256 + kbase + cc0_ * 8);       \
        rB1 = *(const bf16x8*)(ow + (size_t)(c0g + row1_) * 256 + kbase + cc1_ * 8);       \
    }
#define WRITET(buf)                                                                        \
    {                                                                                      \
        *(bf16x8*)&As[buf][row0_ * SA + cc0_ * 8] = rA0;                                   \
        *(bf16x8*)&As[buf][row1_ * SA + cc1_ * 8] = rA1;                                   \
        *(bf16x8*)&Bs[buf][row0_ * SA + cc0_ * 8] = rB0;                                   \
        *(bf16x8*)&Bs[buf][row1_ * SA + cc1_ * 8] = rB1;                                   \
    }

    for (int cg = 0; cg < 8; cg++) {
        LOADT(cg, 0);
        WRITET(0);
        f32x4 acc[4][4] = {};
        for (int kt = 0; kt < 8; kt++) {
            int buf = kt & 1;
            if (kt < 7) LOADT(cg, kt + 1);
            __syncthreads();
            bf16x8 a[4], b[4];
#pragma unroll
            for (int mi = 0; mi < 4; mi++)
                a[mi] = *(const bf16x8*)&As[buf][(wr + mi * 16 + rl) * SA + g * 8];
#pragma unroll
            for (int ni = 0; ni < 4; ni++)
                b[ni] = *(const bf16x8*)&Bs[buf][(wc + ni * 16 + rl) * SA + g * 8];
#pragma unroll
            for (int ni = 0; ni < 4; ni++)
#pragma unroll
                for (int mi = 0; mi < 4; mi++) acc[mi][ni] = MFMA(a[mi], b[ni], acc[mi][ni]);
            if (kt < 7) WRITET(buf ^ 1);
        }
        int c0g = cg * 128;
        int cl = lane & 15;
#pragma unroll
        for (int ni = 0; ni < 4; ni++) {
            float bv = bias[c0g + wc + ni * 16 + cl];
#pragma unroll
            for (int mi = 0; mi < 4; mi++)
#pragma unroll
                for (int r = 0; r < 4; r++)
                    out[(size_t)(r0 + wr + mi * 16 + g * 4 + r) * VV + c0g + wc + ni * 16 + cl] =
                        acc[mi][ni][r] + bv;
        }
        __syncthreads();
    }
#undef LOADT
#undef WRITET
}

// ---------------------------------------------------------------------------
extern "C" void kernel_launch(void* const* d_in, const int* in_sizes, int n_in,
                              void* d_out, int out_size, void* d_ws, size_t ws_size,
                              hipStream_t stream) {
    const int* chars        = (const int*)d_in[0];
    const float* byte_embed = (const float*)d_in[1];
    const float* table0     = (const float*)d_in[2];
    const float* table1     = (const float*)d_in[3];
    const float* table2     = (const float*)d_in[4];
    const float* table3     = (const float*)d_in[5];
    const float* cond_w     = (const float*)d_in[6];
    const float* conv_w     = (const float*)d_in[7];
    const float* conv_b     = (const float*)d_in[8];
    const float* gate_w     = (const float*)d_in[9];
    const float* gate_b     = (const float*)d_in[10];
    const float* inpr_w     = (const float*)d_in[11];
    const float* inpr_b     = (const float*)d_in[12];
    const float* outpr_w    = (const float*)d_in[13];
    const float* outpr_b    = (const float*)d_in[14];
    const float* scan_ln_w  = (const float*)d_in[15];
    const float* scan_ln_b  = (const float*)d_in[16];
    const float* inp_w      = (const float*)d_in[17];
    const float* inp_b      = (const float*)d_in[18];
    const float* r_w1       = (const float*)d_in[19];
    const float* r_w2       = (const float*)d_in[20];
    const float* r_proj     = (const float*)d_in[21];
    const float* r_ln_w     = (const float*)d_in[22];
    const float* r_ln_b     = (const float*)d_in[23];
    const float* out_w      = (const float*)d_in[24];
    const float* out_b      = (const float*)d_in[25];

    // ws layout with lifetimes (peak 61.9 MB):
    //   wbf  [0, 0.97M)       prep..end
    //   hf   [1M, 22M)        featgates..post (f32, stride 80)
    //   raw  [22M, 24.1M)     hash..featgates (disjoint from Ag: featgates
    //                          reads raw while writing Ag)
    //   Ag   [24.1M, 32.5M)   featgates..scan
    //   Dr   [32.5M, 40.9M)   featgates..scan
    //   st   [40.9M, 49.3M)   scan..post
    //   h1p  [49.3M, 61.9M)   post..gmlp_f (bf16, stride 96)
    //   h3b  [1M, 34.6M)      gmlp_f..out4 (over hf/raw/Ag: all dead after
    //                          post/scan; disjoint from h1p)
    char* ws = (char*)d_ws;
    u16*   wbf = (u16*)(ws + 0);
    u16*   w1b = wbf;
    u16*   w2b = wbf + 65536;
    u16*   wpb = wbf + 131072;
    u16*   owb = wbf + 196608;
    u16*   iwb = wbf + 458752;
    float* hf  = (float*)(ws + 1048576);
    float* raw = (float*)(ws + 23068672);
    float* Ag  = (float*)(ws + 25165824);
    float* Dr  = (float*)(ws + 33554432);
    float* st  = (float*)(ws + 41943040);
    u16*   h1p = (u16*)(ws + 50331648);
    u16*   h3b = (u16*)(ws + 1048576);
    float* out = (float*)d_out;

    k_prep <<<1888, 256, 0, stream>>>(r_w1, r_w2, r_proj, out_w, inp_w, wbf);
    k_hash <<<256, 256, 0, stream>>>(chars, table0, table1, table2, table3, cond_w, raw);
    k_featgates<<<1024, 256, 0, stream>>>(chars, byte_embed, raw, conv_w, conv_b,
                                          gate_w, gate_b, inpr_w, inpr_b, hf, Ag, Dr);
    k_scan_par<<<1024, 64, 0, stream>>>(Ag, Dr, st);
    k_post <<<256, 256, 0, stream>>>(st, hf, outpr_w, outpr_b, scan_ln_w, scan_ln_b, h1p);
    k_gmlp_f<<<1024, 256, 0, stream>>>(h1p, iwb, inp_b, w1b, w2b, wpb, r_ln_w, r_ln_b, h3b);
    k_out4 <<<512, 256, 0, stream>>>(h3b, owb, out_b, out);
}